// Round 3
// baseline (179.005 us; speedup 1.0000x reference)
//
#include <hip/hip_runtime.h>

#define HW    256
#define HW2   (HW*HW)
#define C     32
#define CPB   8          // channels per block (channel split = 4)

__global__ __launch_bounds__(128, 2) void ddown_kernel(
    const float* __restrict__ x,
    const float* __restrict__ kern,
    float* __restrict__ out)
{
    const int t   = threadIdx.x;     // 128 threads = 2 waves
    const int txq = t & 7;           // 8 column-groups of 4 outputs
    const int ty  = t >> 3;          // 16 rows
    const int w0  = blockIdx.x * 32;
    const int h0  = blockIdx.y * 16;
    const int b   = blockIdx.z >> 2;
    const int c0  = (blockIdx.z & 3) * CPB;

    const int h = h0 + ty;           // output row
    const int c = w0 + txq * 4;      // first output col (multiple of 4)

    // ---- softmax weights for this thread's 4 pixels (unnormalized; fold 1/S at end) ----
    const float* kb = kern + (size_t)b * 25 * HW2 + h * HW + c;
    float4 wt[25];
    float sx = 0.f, sy = 0.f, sz = 0.f, sw = 0.f;
#pragma unroll
    for (int j = 0; j < 25; ++j) {
        float4 v = *(const float4*)(kb + (size_t)j * HW2);
        v.x = __expf(v.x); v.y = __expf(v.y); v.z = __expf(v.z); v.w = __expf(v.w);
        sx += v.x; sy += v.y; sz += v.z; sw += v.w;
        wt[j] = v;
    }
    const float ix = 1.f / sx, iy = 1.f / sy, iz = 1.f / sz, iw = 1.f / sw;

    // ---- precomputed clamped offsets (dwords), constant across channels ----
    int row_off[5];
#pragma unroll
    for (int di = 0; di < 5; ++di) {
        int hr = h - 2 + di;
        hr = min(max(hr, 0), HW - 1);
        row_off[di] = hr * HW;
    }
    int colp[4];
#pragma unroll
    for (int k = 0; k < 4; ++k) {
        int p = (c - 2 + 2 * k) / 2;          // c even -> exact
        p = min(max(p, 0), HW / 2 - 1);
        colp[k] = p * 2;                      // dword offset, 8B aligned
    }
    const bool lfix = (c == 0);               // window col -1 needs x0 (clamped pair gave x1)
    const bool rfix = (c == HW - 4);          // window col 256 needs x255 (clamped pair gave x254)

    const float* xc = x + (size_t)(b * C + c0) * HW2;
    float*       ob = out + (size_t)(b * C + c0) * HW2 + h * HW + c;

    for (int cc = 0; cc < CPB; ++cc) {
        // load the 5x8 window as 20 float2 pairs (L1-served; heavy inter-lane overlap)
        float2 p[5][4];
#pragma unroll
        for (int di = 0; di < 5; ++di)
#pragma unroll
            for (int k = 0; k < 4; ++k)
                p[di][k] = *(const float2*)(xc + row_off[di] + colp[k]);

        float ax = 0.f, ay = 0.f, az = 0.f, aw = 0.f;
#pragma unroll
        for (int di = 0; di < 5; ++di) {
            float w8[8] = { p[di][0].x, p[di][0].y, p[di][1].x, p[di][1].y,
                            p[di][2].x, p[di][2].y, p[di][3].x, p[di][3].y };
            w8[1] = lfix ? w8[0] : w8[1];     // edge-replicate fixups (1 select/side)
            w8[6] = rfix ? w8[5] : w8[6];
#pragma unroll
            for (int dj = 0; dj < 5; ++dj) {
                float4 wv = wt[di * 5 + dj];
                ax += wv.x * w8[dj + 0];
                ay += wv.y * w8[dj + 1];
                az += wv.z * w8[dj + 2];
                aw += wv.w * w8[dj + 3];
            }
        }
        float4 res = { ax * ix, ay * iy, az * iz, aw * iw };
        *(float4*)ob = res;
        xc += HW2;
        ob += HW2;
    }
}

extern "C" void kernel_launch(void* const* d_in, const int* in_sizes, int n_in,
                              void* d_out, int out_size, void* d_ws, size_t ws_size,
                              hipStream_t stream) {
    const float* x    = (const float*)d_in[0];
    const float* kern = (const float*)d_in[1];
    float* out        = (float*)d_out;

    dim3 grid(HW / 32, HW / 16, 4 * 4);   // (8, 16, 16) = 2048 blocks x 128 threads
    ddown_kernel<<<grid, 128, 0, stream>>>(x, kern, out);
}

// Round 4
// 123.216 us; speedup vs baseline: 1.4528x; 1.4528x over previous
//
#include <hip/hip_runtime.h>

#define HW    256
#define HW2   (HW*HW)
#define C     32
#define CPB   8          // channels per block (channel split = 4)

__global__ __launch_bounds__(256) void ddown_kernel(
    const float* __restrict__ x,
    const float* __restrict__ kern,
    float* __restrict__ out)
{
    const int t   = threadIdx.x;
    const int txq = t & 15;          // 16 column-groups of 4 outputs -> 64 cols
    const int ty  = t >> 4;          // 16 rows
    const int w0  = blockIdx.x * 64;
    const int h0  = blockIdx.y * 16;
    const int b   = blockIdx.z >> 2;
    const int c0  = (blockIdx.z & 3) * CPB;

    const int h = h0 + ty;           // output row
    const int c = w0 + txq * 4;      // first output col (multiple of 4)

    // ---- softmax weights for this thread's 4 pixels (unnormalized; fold 1/S at end) ----
    const float* kb = kern + (size_t)b * 25 * HW2 + h * HW + c;
    float4 wt[25];
    float sx = 0.f, sy = 0.f, sz = 0.f, sw = 0.f;
#pragma unroll
    for (int j = 0; j < 25; ++j) {
        float4 v = *(const float4*)(kb + (size_t)j * HW2);
        v.x = __expf(v.x); v.y = __expf(v.y); v.z = __expf(v.z); v.w = __expf(v.w);
        sx += v.x; sy += v.y; sz += v.z; sw += v.w;
        wt[j] = v;
    }
    const float ix = 1.f / sx, iy = 1.f / sy, iz = 1.f / sz, iw = 1.f / sw;

    // ---- clamped offsets (dwords), constant across channels ----
    int row_off[5];
#pragma unroll
    for (int di = 0; di < 5; ++di) {
        int hr = h - 2 + di;
        hr = min(max(hr, 0), HW - 1);
        row_off[di] = hr * HW;
    }
    int colp[4];
#pragma unroll
    for (int k = 0; k < 4; ++k) {
        int p = (c - 2 + 2 * k) / 2;          // c even -> exact
        p = min(max(p, 0), HW / 2 - 1);
        colp[k] = p * 2;                      // dword offset, 8B aligned
    }
    const bool lfix = (c == 0);               // edge-replicate fixups (verified in R3)
    const bool rfix = (c == HW - 4);

    const float* xc = x + (size_t)(b * C + c0) * HW2;
    float*       ob = out + (size_t)(b * C + c0) * HW2 + h * HW + c;

    for (int cc = 0; cc < CPB; ++cc) {
        float ax = 0.f, ay = 0.f, az = 0.f, aw = 0.f;
#pragma unroll
        for (int di = 0; di < 5; ++di) {
            const float* r = xc + row_off[di];
            float2 q0 = *(const float2*)(r + colp[0]);
            float2 q1 = *(const float2*)(r + colp[1]);
            float2 q2 = *(const float2*)(r + colp[2]);
            float2 q3 = *(const float2*)(r + colp[3]);
            float e0 = q0.x, e1 = q0.y, e2 = q1.x, e3 = q1.y;
            float e4 = q2.x, e5 = q2.y, e6 = q3.x, e7 = q3.y;
            e1 = lfix ? e0 : e1;
            e6 = rfix ? e5 : e6;

            float4 w0v = wt[di * 5 + 0];
            float4 w1v = wt[di * 5 + 1];
            float4 w2v = wt[di * 5 + 2];
            float4 w3v = wt[di * 5 + 3];
            float4 w4v = wt[di * 5 + 4];
            ax += w0v.x * e0 + w1v.x * e1 + w2v.x * e2 + w3v.x * e3 + w4v.x * e4;
            ay += w0v.y * e1 + w1v.y * e2 + w2v.y * e3 + w3v.y * e4 + w4v.y * e5;
            az += w0v.z * e2 + w1v.z * e3 + w2v.z * e4 + w3v.z * e5 + w4v.z * e6;
            aw += w0v.w * e3 + w1v.w * e4 + w2v.w * e5 + w3v.w * e6 + w4v.w * e7;
        }
        float4 res = { ax * ix, ay * iy, az * iz, aw * iw };
        *(float4*)ob = res;
        xc += HW2;
        ob += HW2;
    }
}

extern "C" void kernel_launch(void* const* d_in, const int* in_sizes, int n_in,
                              void* d_out, int out_size, void* d_ws, size_t ws_size,
                              hipStream_t stream) {
    const float* x    = (const float*)d_in[0];
    const float* kern = (const float*)d_in[1];
    float* out        = (float*)d_out;

    dim3 grid(HW / 64, HW / 16, 4 * 4);   // (4, 16, 16) = 1024 blocks x 256 threads
    ddown_kernel<<<grid, 256, 0, stream>>>(x, kern, out);
}